// Round 5
// baseline (840.860 us; speedup 1.0000x reference)
//
#include <hip/hip_runtime.h>
#include <hip/hip_bf16.h>

#define N_NODES 100000
#define N_EDGES 1600000
#define HDIM    128
#define NLAYER  6
#define NGRAPH  128
#define NCLASS  10
#define BN_EPS  1e-5f

#define SCAN_CHUNK 1024
#define SCAN_NB    ((N_NODES + SCAN_CHUNK - 1) / SCAN_CHUNK)   // 98
#define POOL_SPLIT 16
#define BUCKET_W 12500                                          // nodes per XCD bucket

#define GBM 128
#define NBLK_G ((N_NODES + GBM - 1) / GBM)                     // 782

typedef __attribute__((ext_vector_type(8))) short short8v;
typedef __attribute__((ext_vector_type(4))) float f32x4;

__device__ __forceinline__ float b2f(unsigned short h) {
    return __uint_as_float(((unsigned int)h) << 16);
}
__device__ __forceinline__ unsigned short f2b(float f) {
    unsigned int u = __float_as_uint(f);
    u += 0x7FFF + ((u >> 16) & 1);          // RNE
    return (unsigned short)(u >> 16);
}
__device__ __forceinline__ void gl_lds16(const void* g, void* l) {
    __builtin_amdgcn_global_load_lds((const __attribute__((address_space(1))) unsigned int*)g,
                                     (__attribute__((address_space(3))) unsigned int*)l,
                                     16, 0, 0);
}
__device__ __forceinline__ short8v bn_pack(short8v v, float4 scA, float4 scB,
                                           float4 shA, float4 shB) {
    short8v o;
    o[0] = (short)f2b(fmaxf(0.f, b2f((unsigned short)v[0]) * scA.x + shA.x));
    o[1] = (short)f2b(fmaxf(0.f, b2f((unsigned short)v[1]) * scA.y + shA.y));
    o[2] = (short)f2b(fmaxf(0.f, b2f((unsigned short)v[2]) * scA.z + shA.z));
    o[3] = (short)f2b(fmaxf(0.f, b2f((unsigned short)v[3]) * scA.w + shA.w));
    o[4] = (short)f2b(fmaxf(0.f, b2f((unsigned short)v[4]) * scB.x + shB.x));
    o[5] = (short)f2b(fmaxf(0.f, b2f((unsigned short)v[5]) * scB.y + shB.y));
    o[6] = (short)f2b(fmaxf(0.f, b2f((unsigned short)v[6]) * scB.z + shB.z));
    o[7] = (short)f2b(fmaxf(0.f, b2f((unsigned short)v[7]) * scB.w + shB.w));
    return o;
}

// ---------------- CSR build (XCD-bucketed writes, int4 scans) ----------------

__global__ void __launch_bounds__(256) k_deg_b(const int* __restrict__ dst,
                                               int* __restrict__ deg) {
    const int res = blockIdx.x & 7;
    const int lo  = res * BUCKET_W;
    const int bi  = blockIdx.x >> 3;
    const int stride = (gridDim.x >> 3) * 256;
    const int4* d4p = (const int4*)dst;
    for (int i = bi * 256 + threadIdx.x; i < N_EDGES / 4; i += stride) {
        int4 d = d4p[i];
        if ((unsigned)(d.x - lo) < BUCKET_W) atomicAdd(&deg[d.x], 1);
        if ((unsigned)(d.y - lo) < BUCKET_W) atomicAdd(&deg[d.y], 1);
        if ((unsigned)(d.z - lo) < BUCKET_W) atomicAdd(&deg[d.z], 1);
        if ((unsigned)(d.w - lo) < BUCKET_W) atomicAdd(&deg[d.w], 1);
    }
}

__global__ void __launch_bounds__(256) k_fill_b(const int* __restrict__ src,
                                                const int* __restrict__ dst,
                                                const int* __restrict__ row_off,
                                                int* __restrict__ cursor,
                                                int* __restrict__ col) {
    const int res = blockIdx.x & 7;
    const int lo  = res * BUCKET_W;
    const int bi  = blockIdx.x >> 3;
    const int stride = (gridDim.x >> 3) * 256;
    const int4* d4p = (const int4*)dst;
    const int4* s4p = (const int4*)src;
    for (int i = bi * 256 + threadIdx.x; i < N_EDGES / 4; i += stride) {
        int4 d = d4p[i];
        bool m0 = (unsigned)(d.x - lo) < BUCKET_W;
        bool m1 = (unsigned)(d.y - lo) < BUCKET_W;
        bool m2 = (unsigned)(d.z - lo) < BUCKET_W;
        bool m3 = (unsigned)(d.w - lo) < BUCKET_W;
        if (m0 | m1 | m2 | m3) {
            int4 s = s4p[i];
            if (m0) { int pos = row_off[d.x] + atomicAdd(&cursor[d.x], 1); col[pos] = s.x; }
            if (m1) { int pos = row_off[d.y] + atomicAdd(&cursor[d.y], 1); col[pos] = s.y; }
            if (m2) { int pos = row_off[d.z] + atomicAdd(&cursor[d.z], 1); col[pos] = s.z; }
            if (m3) { int pos = row_off[d.w] + atomicAdd(&cursor[d.w], 1); col[pos] = s.w; }
        }
    }
}

__global__ void k_blocksum(const int* __restrict__ deg, int* __restrict__ partial) {
    int b = blockIdx.x, t = threadIdx.x;
    int s = 0;
    for (int i = 0; i < 4; ++i) {
        int g = b * SCAN_CHUNK + t * 4 + i;
        if (g < N_NODES) s += deg[g];
    }
    __shared__ int red[256];
    red[t] = s; __syncthreads();
    for (int off = 128; off > 0; off >>= 1) {
        if (t < off) red[t] += red[t + off];
        __syncthreads();
    }
    if (t == 0) partial[b] = red[0];
}

__global__ void k_scanpart(int* __restrict__ partial) {
    if (threadIdx.x == 0 && blockIdx.x == 0) {
        int acc = 0;
        for (int i = 0; i < SCAN_NB; ++i) { int v = partial[i]; partial[i] = acc; acc += v; }
    }
}

__global__ void k_scan2(const int* __restrict__ deg, const int* __restrict__ partial,
                        int* __restrict__ row_off) {
    int b = blockIdx.x, t = threadIdx.x;
    int base = b * SCAN_CHUNK;
    int v[4]; int s = 0;
    for (int i = 0; i < 4; ++i) {
        int g = base + t * 4 + i;
        v[i] = (g < N_NODES) ? deg[g] : 0;
        s += v[i];
    }
    __shared__ int ts[256];
    ts[t] = s; __syncthreads();
    for (int off = 1; off < 256; off <<= 1) {
        int x = (t >= off) ? ts[t - off] : 0;
        __syncthreads();
        ts[t] += x;
        __syncthreads();
    }
    int excl = (t > 0 ? ts[t - 1] : 0) + partial[b];
    for (int i = 0; i < 4; ++i) {
        int g = base + t * 4 + i;
        if (g < N_NODES) row_off[g] = excl;
        excl += v[i];
    }
    if (b == 0 && t == 0) row_off[N_NODES] = N_EDGES;
}

// ---------------- one-time converts ----------------

__global__ void __launch_bounds__(256) k_cvt_x(const float* __restrict__ x,
                                               unsigned short* __restrict__ Xb) {
    int idx = blockIdx.x * 256 + threadIdx.x;          // < N*H/4
    float4 v = ((const float4*)x)[idx];
    ushort4 o = { f2b(v.x), f2b(v.y), f2b(v.z), f2b(v.w) };
    ((ushort4*)Xb)[idx] = o;
}

// Wtb[l][n][kk] (kk<128 -> Wl[l][kk][n], else Wr[l][kk-128][n]), bf16
__global__ void __launch_bounds__(256) k_cvt_w(const float* __restrict__ Wl,
                                               const float* __restrict__ Wr,
                                               unsigned short* __restrict__ Wtb) {
    int idx = blockIdx.x * 256 + threadIdx.x;          // < 6*128*256
    int kk = idx & 255;
    int n  = (idx >> 8) & 127;
    int l  = idx >> 15;
    float v = (kk < HDIM) ? Wl[l * HDIM * HDIM + kk * HDIM + n]
                          : Wr[l * HDIM * HDIM + (kk - HDIM) * HDIM + n];
    Wtb[idx] = f2b(v);
}

// ---------------- aggregation ----------------

// 16 nodes/block, 16 threads/node, ushort8 (16B) per thread; 8-deep unrolled gather
__global__ void __launch_bounds__(256) k_agg(const unsigned short* __restrict__ Xb,
                                             const int* __restrict__ row_off,
                                             const int* __restrict__ col,
                                             unsigned short* __restrict__ AGGb) {
    int node = blockIdx.x * 16 + (threadIdx.x >> 4);
    int t = threadIdx.x & 15;
    int s = row_off[node], e = row_off[node + 1];
    float a[8] = {};
    int p = s;
    for (; p + 8 <= e; p += 8) {
        int nb[8];
#pragma unroll
        for (int j = 0; j < 8; ++j) nb[j] = col[p + j];
        short8v v[8];
#pragma unroll
        for (int j = 0; j < 8; ++j)
            v[j] = *(const short8v*)(Xb + (size_t)nb[j] * HDIM + t * 8);
#pragma unroll
        for (int j = 0; j < 8; ++j)
#pragma unroll
            for (int k = 0; k < 8; ++k) a[k] += b2f((unsigned short)v[j][k]);
    }
    if (p + 4 <= e) {
        int nb[4];
#pragma unroll
        for (int j = 0; j < 4; ++j) nb[j] = col[p + j];
        short8v v[4];
#pragma unroll
        for (int j = 0; j < 4; ++j)
            v[j] = *(const short8v*)(Xb + (size_t)nb[j] * HDIM + t * 8);
#pragma unroll
        for (int j = 0; j < 4; ++j)
#pragma unroll
            for (int k = 0; k < 8; ++k) a[k] += b2f((unsigned short)v[j][k]);
        p += 4;
    }
    for (; p < e; ++p) {
        int n0 = col[p];
        short8v v0 = *(const short8v*)(Xb + (size_t)n0 * HDIM + t * 8);
#pragma unroll
        for (int k = 0; k < 8; ++k) a[k] += b2f((unsigned short)v0[k]);
    }
    float w = (e > s) ? 1.0f / (float)(e - s) : 0.f;
    short8v o;
#pragma unroll
    for (int k = 0; k < 8; ++k) o[k] = (short)f2b(a[k] * w);
    *(short8v*)(AGGb + (size_t)node * HDIM + t * 8) = o;
}

// gather raw H, apply BN(scsh)+ReLU on the fly; 8-deep unrolled
__global__ void __launch_bounds__(256) k_agg_bn(const unsigned short* __restrict__ Hb,
                                                const float* __restrict__ scsh,
                                                const int* __restrict__ row_off,
                                                const int* __restrict__ col,
                                                unsigned short* __restrict__ AGGb) {
    int node = blockIdx.x * 16 + (threadIdx.x >> 4);
    int t = threadIdx.x & 15;
    int c8 = t * 8;
    float sc[8], sh[8];
#pragma unroll
    for (int k = 0; k < 8; ++k) { sc[k] = scsh[c8 + k]; sh[k] = scsh[HDIM + c8 + k]; }
    int s = row_off[node], e = row_off[node + 1];
    float a[8] = {};
    int p = s;
    for (; p + 8 <= e; p += 8) {
        int nb[8];
#pragma unroll
        for (int j = 0; j < 8; ++j) nb[j] = col[p + j];
        short8v v[8];
#pragma unroll
        for (int j = 0; j < 8; ++j)
            v[j] = *(const short8v*)(Hb + (size_t)nb[j] * HDIM + c8);
#pragma unroll
        for (int j = 0; j < 8; ++j)
#pragma unroll
            for (int k = 0; k < 8; ++k)
                a[k] += fmaxf(0.f, b2f((unsigned short)v[j][k]) * sc[k] + sh[k]);
    }
    if (p + 4 <= e) {
        int nb[4];
#pragma unroll
        for (int j = 0; j < 4; ++j) nb[j] = col[p + j];
        short8v v[4];
#pragma unroll
        for (int j = 0; j < 4; ++j)
            v[j] = *(const short8v*)(Hb + (size_t)nb[j] * HDIM + c8);
#pragma unroll
        for (int j = 0; j < 4; ++j)
#pragma unroll
            for (int k = 0; k < 8; ++k)
                a[k] += fmaxf(0.f, b2f((unsigned short)v[j][k]) * sc[k] + sh[k]);
        p += 4;
    }
    for (; p < e; ++p) {
        int n0 = col[p];
        short8v v0 = *(const short8v*)(Hb + (size_t)n0 * HDIM + c8);
#pragma unroll
        for (int k = 0; k < 8; ++k)
            a[k] += fmaxf(0.f, b2f((unsigned short)v0[k]) * sc[k] + sh[k]);
    }
    float w = (e > s) ? 1.0f / (float)(e - s) : 0.f;
    short8v o;
#pragma unroll
    for (int k = 0; k < 8; ++k) o[k] = (short)f2b(a[k] * w);
    *(short8v*)(AGGb + (size_t)node * HDIM + c8) = o;
}

// ---------------- GEMMs (128 rows/block, K=256, dbuf, fused BN stats) ----------------

// layer 0: A = [AGGb | Xb], both gl_lds
__global__ void __launch_bounds__(256) k_gemm_l0(const unsigned short* __restrict__ AGGb,
                                                 const unsigned short* __restrict__ Xb,
                                                 const unsigned short* __restrict__ Wtb,
                                                 const float* __restrict__ bl,
                                                 unsigned short* __restrict__ Hb,
                                                 float* __restrict__ pstat) {
    __shared__ __align__(16) char smem[32768];
    const int tid  = threadIdx.x;
    const int bm   = blockIdx.x * GBM;
    const int wv   = tid >> 6;
    const int lane = tid & 63;
    const int li   = lane & 15, hi = lane >> 4;

    f32x4 acc[2][8] = {};

    auto stage = [&](int b, int step) {
        const unsigned short* Asrc = (step < 4) ? AGGb : Xb;
        const int kk0 = (step & 3) * 32;
        char* base = smem + b * 16384;
#pragma unroll
        for (int q = 0; q < 2; ++q) {
            int s = q * 256 + tid;
            int r = s >> 2, sk = s & 3;
            int row = bm + r; if (row >= N_NODES) row = N_NODES - 1;
            gl_lds16((const char*)(Asrc + (size_t)row * HDIM + kk0) + (((sk ^ (r & 3)) & 3) << 4),
                     base + (q * 4 + wv) * 1024);
        }
        const int k0 = step * 32;
#pragma unroll
        for (int q = 0; q < 2; ++q) {
            int s = q * 256 + tid;
            int n = s >> 2, sk = s & 3;
            gl_lds16((const char*)(Wtb + (size_t)n * 256 + k0) + (((sk ^ (n & 3)) & 3) << 4),
                     base + 8192 + (q * 4 + wv) * 1024);
        }
    };

    stage(0, 0);
    __syncthreads();

    int buf = 0;
    for (int step = 0; step < 8; ++step) {
        if (step < 7) stage(buf ^ 1, step + 1);
        char* bA = smem + buf * 16384;
        char* bW = bA + 8192;
        short8v afr[2], bfr[8];
#pragma unroll
        for (int m = 0; m < 2; ++m) {
            int r = wv * 32 + m * 16 + li;
            afr[m] = *(const short8v*)(bA + r * 64 + ((hi ^ (r & 3)) << 4));
        }
#pragma unroll
        for (int nf = 0; nf < 8; ++nf) {
            int n = nf * 16 + li;
            bfr[nf] = *(const short8v*)(bW + n * 64 + ((hi ^ (n & 3)) << 4));
        }
#pragma unroll
        for (int m = 0; m < 2; ++m)
#pragma unroll
            for (int nf = 0; nf < 8; ++nf)
                acc[m][nf] = __builtin_amdgcn_mfma_f32_16x16x32_bf16(afr[m], bfr[nf],
                                                                     acc[m][nf], 0, 0, 0);
        __syncthreads();
        buf ^= 1;
    }

    float* st = (float*)smem;
#pragma unroll
    for (int nf = 0; nf < 8; ++nf) {
        int c = nf * 16 + li;
        float bb = bl[c];
        float ls = 0.f, lq = 0.f;
#pragma unroll
        for (int m = 0; m < 2; ++m) {
            int row0 = bm + wv * 32 + m * 16 + hi * 4;
#pragma unroll
            for (int j = 0; j < 4; ++j) {
                int row = row0 + j;
                if (row < N_NODES) {
                    float v = acc[m][nf][j] + bb;
                    Hb[(size_t)row * HDIM + c] = f2b(v);
                    ls += v; lq += v * v;
                }
            }
        }
        ls += __shfl_xor(ls, 16); ls += __shfl_xor(ls, 32);
        lq += __shfl_xor(lq, 16); lq += __shfl_xor(lq, 32);
        if (hi == 0) {
            st[wv * 128 + c] = ls;
            st[512 + wv * 128 + c] = lq;
        }
    }
    __syncthreads();
    if (tid < 128) {
        float s = st[tid] + st[128 + tid] + st[256 + tid] + st[384 + tid];
        pstat[blockIdx.x * 256 + tid] = s;
    } else {
        int c = tid - 128;
        float q = st[512 + c] + st[640 + c] + st[768 + c] + st[896 + c];
        pstat[blockIdx.x * 256 + tid] = q;
    }
}

// layers 1..5: A = [AGGb | bn_relu(Hprev)] — second half reg-staged with transform
__global__ void __launch_bounds__(256) k_gemm_fuse(const unsigned short* __restrict__ AGGb,
                                                   const unsigned short* __restrict__ Hprev,
                                                   const float* __restrict__ scsh,
                                                   const unsigned short* __restrict__ Wtb,
                                                   const float* __restrict__ bl,
                                                   unsigned short* __restrict__ Hb,
                                                   float* __restrict__ pstat) {
    __shared__ __align__(16) char smem[32768];
    const int tid  = threadIdx.x;
    const int bm   = blockIdx.x * GBM;
    const int wv   = tid >> 6;
    const int lane = tid & 63;
    const int li   = lane & 15, hi = lane >> 4;
    const int rr   = tid >> 2;            // 0..63
    const int sk   = tid & 3;
    const int swz  = ((sk ^ (rr & 3)) << 4);   // r&3 identical for r=rr and r=rr+64

    f32x4 acc[2][8] = {};

    auto stageW = [&](char* base, int step) {
        const int k0 = step * 32;
#pragma unroll
        for (int q = 0; q < 2; ++q) {
            int n = q * 64 + rr;
            gl_lds16((const char*)(Wtb + (size_t)n * 256 + k0) + swz,
                     base + 8192 + (q * 4 + wv) * 1024);
        }
    };
    auto stageA = [&](char* base, int step) {     // AGGb, steps 0..3
        const int kk0 = step * 32;
#pragma unroll
        for (int q = 0; q < 2; ++q) {
            int r = q * 64 + rr;
            int row = bm + r; if (row >= N_NODES) row = N_NODES - 1;
            gl_lds16((const char*)(AGGb + (size_t)row * HDIM + kk0) + swz,
                     base + (q * 4 + wv) * 1024);
        }
    };

    stageA(smem, 0); stageW(smem, 0);
    __syncthreads();

    int buf = 0;
    for (int step = 0; step < 8; ++step) {
        char* cur = smem + buf * 16384;
        char* nxt = smem + (buf ^ 1) * 16384;
        const int ns = step + 1;
        short8v rv0, rv1;
        int c0 = 0;
        bool regstage = false;
        if (step < 7) {
            stageW(nxt, ns);
            if (ns < 4) {
                stageA(nxt, ns);
            } else {
                regstage = true;
                c0 = ns * 32 - 128 + sk * 8;
                int row0 = bm + rr;      if (row0 >= N_NODES) row0 = N_NODES - 1;
                int row1 = bm + 64 + rr; if (row1 >= N_NODES) row1 = N_NODES - 1;
                rv0 = *(const short8v*)(Hprev + (size_t)row0 * HDIM + c0);
                rv1 = *(const short8v*)(Hprev + (size_t)row1 * HDIM + c0);
            }
        }

        short8v afr[2], bfr[8];
#pragma unroll
        for (int m = 0; m < 2; ++m) {
            int r = wv * 32 + m * 16 + li;
            afr[m] = *(const short8v*)(cur + r * 64 + ((hi ^ (r & 3)) << 4));
        }
#pragma unroll
        for (int nf = 0; nf < 8; ++nf) {
            int n = nf * 16 + li;
            bfr[nf] = *(const short8v*)(cur + 8192 + n * 64 + ((hi ^ (n & 3)) << 4));
        }
#pragma unroll
        for (int m = 0; m < 2; ++m)
#pragma unroll
            for (int nf = 0; nf < 8; ++nf)
                acc[m][nf] = __builtin_amdgcn_mfma_f32_16x16x32_bf16(afr[m], bfr[nf],
                                                                     acc[m][nf], 0, 0, 0);

        if (regstage) {
            float4 scA = *(const float4*)&scsh[c0];
            float4 scB = *(const float4*)&scsh[c0 + 4];
            float4 shA = *(const float4*)&scsh[HDIM + c0];
            float4 shB = *(const float4*)&scsh[HDIM + c0 + 4];
            *(short8v*)(nxt + rr * 64 + swz)        = bn_pack(rv0, scA, scB, shA, shB);
            *(short8v*)(nxt + (64 + rr) * 64 + swz) = bn_pack(rv1, scA, scB, shA, shB);
        }
        __syncthreads();
        buf ^= 1;
    }

    float* st = (float*)smem;
#pragma unroll
    for (int nf = 0; nf < 8; ++nf) {
        int c = nf * 16 + li;
        float bb = bl[c];
        float ls = 0.f, lq = 0.f;
#pragma unroll
        for (int m = 0; m < 2; ++m) {
            int row0 = bm + wv * 32 + m * 16 + hi * 4;
#pragma unroll
            for (int j = 0; j < 4; ++j) {
                int row = row0 + j;
                if (row < N_NODES) {
                    float v = acc[m][nf][j] + bb;
                    Hb[(size_t)row * HDIM + c] = f2b(v);
                    ls += v; lq += v * v;
                }
            }
        }
        ls += __shfl_xor(ls, 16); ls += __shfl_xor(ls, 32);
        lq += __shfl_xor(lq, 16); lq += __shfl_xor(lq, 32);
        if (hi == 0) {
            st[wv * 128 + c] = ls;
            st[512 + wv * 128 + c] = lq;
        }
    }
    __syncthreads();
    if (tid < 128) {
        float s = st[tid] + st[128 + tid] + st[256 + tid] + st[384 + tid];
        pstat[blockIdx.x * 256 + tid] = s;
    } else {
        int c = tid - 128;
        float q = st[512 + c] + st[640 + c] + st[768 + c] + st[896 + c];
        pstat[blockIdx.x * 256 + tid] = q;
    }
}

__global__ void __launch_bounds__(256) k_red1(const float* __restrict__ pstat,
                                              float* __restrict__ red32) {
    int c = threadIdx.x, b = blockIdx.x;
    float s = 0.f;
    for (int r = b; r < NBLK_G; r += 32) s += pstat[r * 256 + c];
    red32[b * 256 + c] = s;
}

__global__ void __launch_bounds__(128) k_stats_final(const float* __restrict__ red32,
                                                     const float* __restrict__ gamma,
                                                     const float* __restrict__ beta,
                                                     float* __restrict__ scsh) {
    int c = threadIdx.x;
    float s = 0.f, q = 0.f;
    for (int r = 0; r < 32; ++r) { s += red32[r * 256 + c]; q += red32[r * 256 + 128 + c]; }
    float mu = s / (float)N_NODES;
    float var = q / (float)N_NODES - mu * mu;
    float rs = rsqrtf(var + BN_EPS);
    float sc = gamma[c] * rs;
    scsh[c] = sc;
    scsh[HDIM + c] = beta[c] - mu * sc;
}

// ---------------- pooling + classifier ----------------

__global__ void k_gbound(const int* __restrict__ batch, int* __restrict__ gb) {
    int t = blockIdx.x * 64 + threadIdx.x;
    if (t > NGRAPH) return;
    int lo = 0, hi = N_NODES;
    while (lo < hi) { int mid = (lo + hi) >> 1; if (batch[mid] < t) lo = mid + 1; else hi = mid; }
    gb[t] = lo;
}

// pool over bn_relu(H_final) applied on the fly
__global__ void __launch_bounds__(128) k_pool_part(const unsigned short* __restrict__ Hb,
                                                   const float* __restrict__ scsh,
                                                   const int* __restrict__ gb,
                                                   float* __restrict__ ppart) {
    int g = blockIdx.x, sp = blockIdx.y;
    int c = threadIdx.x;
    float sc = scsh[c], sh = scsh[HDIM + c];
    int s = gb[g], e = gb[g + 1];
    float acc = 0.f;
    for (int i = s + sp; i < e; i += POOL_SPLIT)
        acc += fmaxf(0.f, b2f(Hb[(size_t)i * HDIM + c]) * sc + sh);
    ppart[(g * POOL_SPLIT + sp) * HDIM + c] = acc;
}

__global__ void __launch_bounds__(128) k_pool_final(const int* __restrict__ gb,
                                                    const float* __restrict__ ppart,
                                                    float* __restrict__ pooled) {
    int g = blockIdx.x, c = threadIdx.x;
    float s = 0.f;
    for (int sp = 0; sp < POOL_SPLIT; ++sp) s += ppart[(g * POOL_SPLIT + sp) * HDIM + c];
    int cnt = gb[g + 1] - gb[g]; if (cnt < 1) cnt = 1;
    pooled[g * HDIM + c] = s / (float)cnt;
}

__global__ void __launch_bounds__(128) k_lin(const float* __restrict__ pooled,
                                             const float* __restrict__ W,
                                             const float* __restrict__ bvec,
                                             float* __restrict__ out) {
    __shared__ float p[HDIM];
    int g = blockIdx.x, t = threadIdx.x;
    p[t] = pooled[g * HDIM + t];
    __syncthreads();
    if (t < NCLASS) {
        float acc = bvec[t];
        for (int k = 0; k < HDIM; ++k) acc += p[k] * W[k * NCLASS + t];
        out[g * NCLASS + t] = acc;
    }
}

// ---------------- launch ----------------

extern "C" void kernel_launch(void* const* d_in, const int* in_sizes, int n_in,
                              void* d_out, int out_size, void* d_ws, size_t ws_size,
                              hipStream_t stream) {
    const float* x     = (const float*)d_in[0];
    const int*   eidx  = (const int*)d_in[1];
    const int*   batch = (const int*)d_in[2];
    const float* Wl    = (const float*)d_in[3];
    const float* bl    = (const float*)d_in[4];
    const float* Wr    = (const float*)d_in[5];
    const float* gamma = (const float*)d_in[6];
    const float* beta  = (const float*)d_in[7];
    const float* linW  = (const float*)d_in[8];
    const float* linb  = (const float*)d_in[9];
    float* out = (float*)d_out;

    const int* src = eidx;
    const int* dst = eidx + N_EDGES;

    char* p = (char*)d_ws;
    auto alloc = [&](size_t bytes) { char* r = p; p += (bytes + 255) & ~(size_t)255; return r; };
    unsigned short* Xb   = (unsigned short*)alloc((size_t)N_NODES * HDIM * 2);
    unsigned short* AGGb = (unsigned short*)alloc((size_t)N_NODES * HDIM * 2);
    unsigned short* HbA  = (unsigned short*)alloc((size_t)N_NODES * HDIM * 2);
    unsigned short* HbB  = (unsigned short*)alloc((size_t)N_NODES * HDIM * 2);
    unsigned short* Wtb  = (unsigned short*)alloc((size_t)NLAYER * 2 * HDIM * HDIM * 2);
    int* row_off = (int*)alloc((N_NODES + 2) * 4);
    int* deg     = (int*)alloc(N_NODES * 4);
    int* cursor  = (int*)alloc(N_NODES * 4);
    int* col     = (int*)alloc((size_t)N_EDGES * 4);
    int* part    = (int*)alloc(SCAN_NB * 4);
    int* gb      = (int*)alloc((NGRAPH + 2) * 4);
    float* pstat = (float*)alloc((size_t)NBLK_G * 256 * 4);
    float* red32 = (float*)alloc(32 * 256 * 4);
    float* scsh  = (float*)alloc(2 * HDIM * 4);
    float* ppart = (float*)alloc((size_t)NGRAPH * POOL_SPLIT * HDIM * 4);
    float* pooled= (float*)alloc(NGRAPH * HDIM * 4);

    // ---- CSR build (XCD-bucketed) ----
    hipMemsetAsync(deg, 0, N_NODES * sizeof(int), stream);
    hipMemsetAsync(cursor, 0, N_NODES * sizeof(int), stream);
    k_deg_b<<<1024, 256, 0, stream>>>(dst, deg);
    k_blocksum<<<SCAN_NB, 256, 0, stream>>>(deg, part);
    k_scanpart<<<1, 64, 0, stream>>>(part);
    k_scan2<<<SCAN_NB, 256, 0, stream>>>(deg, part, row_off);
    k_fill_b<<<1024, 256, 0, stream>>>(src, dst, row_off, cursor, col);

    // ---- one-time converts ----
    k_cvt_x<<<N_NODES * HDIM / 4 / 256, 256, 0, stream>>>(x, Xb);
    k_cvt_w<<<NLAYER * 2 * HDIM * HDIM / 256, 256, 0, stream>>>(Wl, Wr, Wtb);
    k_gbound<<<3, 64, 0, stream>>>(batch, gb);

    // ---- layer 0 ----
    k_agg<<<N_NODES / 16, 256, 0, stream>>>(Xb, row_off, col, AGGb);
    k_gemm_l0<<<NBLK_G, 256, 0, stream>>>(AGGb, Xb, Wtb, bl, HbA, pstat);
    k_red1<<<32, 256, 0, stream>>>(pstat, red32);
    k_stats_final<<<1, 128, 0, stream>>>(red32, gamma, beta, scsh);

    // ---- layers 1..5 ----
    unsigned short* Hcur = HbA;
    for (int l = 1; l < NLAYER; ++l) {
        unsigned short* Hout = (l & 1) ? HbB : HbA;
        k_agg_bn<<<N_NODES / 16, 256, 0, stream>>>(Hcur, scsh, row_off, col, AGGb);
        k_gemm_fuse<<<NBLK_G, 256, 0, stream>>>(
            AGGb, Hcur, scsh, Wtb + (size_t)l * 2 * HDIM * HDIM, bl + (size_t)l * HDIM,
            Hout, pstat);
        k_red1<<<32, 256, 0, stream>>>(pstat, red32);
        k_stats_final<<<1, 128, 0, stream>>>(red32, gamma + (size_t)l * HDIM,
                                             beta + (size_t)l * HDIM, scsh);
        Hcur = Hout;
    }

    // ---- pool + classifier ----
    k_pool_part<<<dim3(NGRAPH, POOL_SPLIT), 128, 0, stream>>>(Hcur, scsh, gb, ppart);
    k_pool_final<<<NGRAPH, 128, 0, stream>>>(gb, ppart, pooled);
    k_lin<<<NGRAPH, 128, 0, stream>>>(pooled, linW, linb, out);
}